// Round 18
// baseline (198.115 us; speedup 1.0000x reference)
//
#include <hip/hip_runtime.h>
#include <hip/hip_bf16.h>
#include <stdint.h>

#define HD 128
#define NQH 16
#define NKVH 8
#define SEQ 2048
#define DMODEL 2048
#define BATCH 2

typedef __attribute__((ext_vector_type(8))) short bf16x8;
typedef __attribute__((ext_vector_type(4))) float f32x4;
typedef __attribute__((ext_vector_type(16))) float f32x16;

__device__ __forceinline__ ushort f2bf(float f){
  union { float f; uint32_t u; } v; v.f = f;
  uint32_t u = v.u;
  return (ushort)((u + 0x7FFFu + ((u >> 16) & 1u)) >> 16);
}
__device__ __forceinline__ float bf2f(ushort h){
  union { uint32_t u; float f; } v; v.u = ((uint32_t)h) << 16; return v.f;
}
__device__ __forceinline__ void gload16(const void* g, void* l){
  __builtin_amdgcn_global_load_lds((const __attribute__((address_space(1))) void*)g,
                                   (__attribute__((address_space(3))) void*)l, 16, 0, 0);
}
__device__ __forceinline__ unsigned int cvtpk(float lo, float hi){
  unsigned int r;
  asm("v_cvt_pk_bf16_f32 %0, %1, %2" : "=v"(r) : "v"(lo), "v"(hi));
  return r;
}

// ---------------- fused fp32 -> bf16 convert (8 elems/thread, cvtpk) ----------------
__global__ void cvtbf3(const float* __restrict__ x, const float* __restrict__ wqkv,
                       const float* __restrict__ wo,
                       ushort* __restrict__ xb, ushort* __restrict__ wqkvb,
                       ushort* __restrict__ wob){
  int bid = blockIdx.x;
  const float* in; ushort* out; int i;
  if (bid < 4096)      { in = x;    out = xb;    i = bid*256 + threadIdx.x; }
  else if (bid < 8192) { in = wqkv; out = wqkvb; i = (bid-4096)*256 + threadIdx.x; }
  else                 { in = wo;   out = wob;   i = (bid-8192)*256 + threadIdx.x; }
  float4 a = ((const float4*)in)[i*2];
  float4 b = ((const float4*)in)[i*2+1];
  uint4 o;
  o.x = cvtpk(a.x, a.y);
  o.y = cvtpk(a.z, a.w);
  o.z = cvtpk(b.x, b.y);
  o.w = cvtpk(b.z, b.w);
  ((uint4*)out)[i] = o;
}

// ---------------- 128x64 bf16 GEMM (O-proj): C = A * B^T, f32 out ----------------
// BM=128, BN=64, BK=64, 4 waves (2x2 of 64x32). LDS 24KB -> grid 1024 = 4 blocks/CU.
// Same proven staging/swizzle pattern as the 128x128 kernel; no sync changes.
__global__ __launch_bounds__(256) void gemm_o(const ushort* __restrict__ A,
                                              const ushort* __restrict__ B,
                                              float* __restrict__ C,
                                              int M, int N, int K){
  __shared__ __align__(16) ushort lA[128*64];
  __shared__ __align__(16) ushort lB[64*64];
  const int tid = threadIdx.x;
  const int l = tid & 63, w = tid >> 6;
  const int nwg = gridDim.x * gridDim.y;
  const int lin = blockIdx.y * gridDim.x + blockIdx.x;
  const int wg = (lin & 7) * (nwg >> 3) + (lin >> 3);
  const int m0 = (wg / gridDim.x) * 128, n0 = (wg % gridDim.x) * 64;
  const int wr = (w >> 1) * 64, wc = (w & 1) * 32;
  f32x4 acc[4][2];
  #pragma unroll
  for (int m=0;m<4;m++)
    #pragma unroll
    for (int n=0;n<2;n++) acc[m][n] = f32x4{0.f,0.f,0.f,0.f};

  const int srow = l >> 3;
  const int scol = ((l & 7) ^ srow) << 3;
  const ushort* gA = A + (size_t)(m0 + w*32 + srow) * K + scol;
  const ushort* gB = B + (size_t)(n0 + w*16 + srow) * K + scol;
  ushort* lAw = &lA[(w*32) * 64];
  ushort* lBw = &lB[(w*16) * 64];

  for (int kt = 0; kt < K; kt += 64){
    __syncthreads();
    #pragma unroll
    for (int j=0;j<4;j++)
      gload16(gA + kt + (size_t)(j*8)*K, lAw + j*8*64);
    #pragma unroll
    for (int j=0;j<2;j++)
      gload16(gB + kt + (size_t)(j*8)*K, lBw + j*8*64);
    __syncthreads();
    #pragma unroll
    for (int kk=0; kk<2; kk++){
      bf16x8 af[4], bb[2];
      #pragma unroll
      for (int m=0;m<4;m++){
        int row = wr + m*16 + (l & 15);
        int slot = (kk*4 + (l >> 4)) ^ (row & 7);
        af[m] = *(const bf16x8*)&lA[row*64 + slot*8];
      }
      #pragma unroll
      for (int n=0;n<2;n++){
        int row = wc + n*16 + (l & 15);
        int slot = (kk*4 + (l >> 4)) ^ (row & 7);
        bb[n] = *(const bf16x8*)&lB[row*64 + slot*8];
      }
      #pragma unroll
      for (int m=0;m<4;m++)
        #pragma unroll
        for (int n=0;n<2;n++)
          acc[m][n] = __builtin_amdgcn_mfma_f32_16x16x32_bf16(af[m], bb[n], acc[m][n], 0,0,0);
    }
  }
  #pragma unroll
  for (int m=0;m<4;m++)
    #pragma unroll
    for (int n=0;n<2;n++)
      #pragma unroll
      for (int r=0;r<4;r++){
        size_t row = (size_t)(m0 + wr + m*16 + (l>>4)*4 + r);
        size_t col = (size_t)(n0 + wc + n*16 + (l & 15));
        C[row*N + col] = acc[m][n][r];
      }
}

// ---------------- 256x256 8-phase bf16 GEMM (QKV): C = A * B^T, bf16 out ----------------
// 2-K-tile unrolled; XCD-aware block swizzle. Sync identical to R4. (R13 verified: 71.7us)
__global__ __launch_bounds__(512, 1) void gemm256_bt(const ushort* __restrict__ A,
                                                     const ushort* __restrict__ B,
                                                     ushort* __restrict__ C,
                                                     int M, int N, int K){
  __shared__ __align__(16) ushort lA[2][256*64];
  __shared__ __align__(16) ushort lB[2][256*64];
  const int tid = threadIdx.x;
  const int l = tid & 63, w = tid >> 6;
  const int wm = w >> 2, wn = w & 3;
  const int nwg = gridDim.x * gridDim.y;
  const int lin = blockIdx.y * gridDim.x + blockIdx.x;
  const int wg = (lin & 7) * (nwg >> 3) + (lin >> 3);
  const int m0 = (wg / gridDim.x) * 256, n0 = (wg % gridDim.x) * 256;
  const int NT = K >> 6;

  const int srow = w*8 + (l >> 3);
  const int scol = ((l & 7) ^ (l >> 3)) << 3;

  const int la15 = l & 15;
  const int sl0 = (((l >> 4)    ) ^ (l & 7)) * 8;
  const int sl1 = ((4 + (l >> 4)) ^ (l & 7)) * 8;

  f32x4 acc[8][4];
  #pragma unroll
  for (int m=0;m<8;m++)
    #pragma unroll
    for (int n=0;n<4;n++) acc[m][n] = f32x4{0.f,0.f,0.f,0.f};

  auto stgA = [&](int t, int h){
    const int bi = t & 1;
    #pragma unroll
    for (int j=0;j<2;j++)
      gload16(A + (size_t)(m0 + h*128 + j*64 + srow)*K + t*64 + scol,
              &lA[bi][(h*128 + j*64 + w*8)*64]);
  };
  auto stgB = [&](int t, int h){
    const int bi = t & 1;
    #pragma unroll
    for (int j=0;j<2;j++)
      gload16(B + (size_t)(n0 + h*128 + j*64 + srow)*K + t*64 + scol,
              &lB[bi][(h*128 + j*64 + w*8)*64]);
  };

  stgA(0,0); stgA(0,1); stgB(0,0); stgB(0,1);
  stgA(1,0); stgB(1,0); stgB(1,1);
  asm volatile("s_waitcnt vmcnt(6)" ::: "memory");
  __builtin_amdgcn_s_barrier();

  for (int t2=0; t2<NT; t2+=2){
    #pragma unroll
    for (int tt=0; tt<2; tt++){
      const int t = t2 + tt;                 // bi == tt (compile-time)
      const ushort* pA = &lA[tt][(wm*128 + la15)*64];
      const ushort* pB = &lB[tt][(wn*64  + la15)*64];
      bf16x8 bfr0[4], bfr1[4];
      #pragma unroll
      for (int q=0; q<4; q++){
        bf16x8 af0[2], af1[2];
        #pragma unroll
        for (int mi2=0; mi2<2; mi2++){
          af0[mi2] = *(const bf16x8*)(pA + (q*32 + mi2*16)*64 + sl0);
          af1[mi2] = *(const bf16x8*)(pA + (q*32 + mi2*16)*64 + sl1);
        }
        if (q == 0){
          #pragma unroll
          for (int ni=0; ni<4; ni++){
            bfr0[ni] = *(const bf16x8*)(pB + ni*16*64 + sl0);
            bfr1[ni] = *(const bf16x8*)(pB + ni*16*64 + sl1);
          }
        }
        if (q == 0 && t+1 < NT) stgA(t+1, 1);
        if (q == 1 && t+2 < NT) stgB(t+2, 0);
        if (q == 2 && t+2 < NT) stgB(t+2, 1);
        __builtin_amdgcn_s_barrier();
        asm volatile("s_waitcnt lgkmcnt(0)" ::: "memory");
        if (q == 3 && t+2 < NT) stgA(t+2, 0);
        __builtin_amdgcn_s_setprio(1);
        #pragma unroll
        for (int mi2=0; mi2<2; mi2++)
          #pragma unroll
          for (int ni=0; ni<4; ni++)
            acc[q*2+mi2][ni] = __builtin_amdgcn_mfma_f32_16x16x32_bf16(
                af0[mi2], bfr0[ni], acc[q*2+mi2][ni], 0,0,0);
        #pragma unroll
        for (int mi2=0; mi2<2; mi2++)
          #pragma unroll
          for (int ni=0; ni<4; ni++)
            acc[q*2+mi2][ni] = __builtin_amdgcn_mfma_f32_16x16x32_bf16(
                af1[mi2], bfr1[ni], acc[q*2+mi2][ni], 0,0,0);
        __builtin_amdgcn_s_setprio(0);
        if (q == 3){
          if (t < NT-2) { asm volatile("s_waitcnt vmcnt(6)" ::: "memory"); }
          else          { asm volatile("s_waitcnt vmcnt(0)" ::: "memory"); }
        }
        __builtin_amdgcn_s_barrier();
      }
    }
  }

  #pragma unroll
  for (int mi=0; mi<8; mi++)
    #pragma unroll
    for (int ni=0; ni<4; ni++)
      #pragma unroll
      for (int r=0; r<4; r++){
        size_t row = (size_t)(m0 + wm*128 + mi*16 + (l>>4)*4 + r);
        size_t col = (size_t)(n0 + wn*64 + ni*16 + (l & 15));
        C[row*N + col] = f2bf(acc[mi][ni][r]);
      }
}

// ---------------- fused RMSNorm+RoPE (blocks 0..12287) + V-transpose (12288..12799) ----------------
__global__ __launch_bounds__(256) void nr_vt(const ushort* __restrict__ qkv,
                                             const float* __restrict__ cosT,
                                             const float* __restrict__ sinT,
                                             const float* __restrict__ qw,
                                             const float* __restrict__ kw,
                                             ushort* __restrict__ Qo,
                                             ushort* __restrict__ Ko,
                                             ushort* __restrict__ vt){
  if (blockIdx.x < 12288){
    int rw = (blockIdx.x * 256 + threadIdx.x) >> 6;
    int l = threadIdx.x & 63;
    int b = l >> 5;
    int li = l & 31;
    int head = rw % 24;
    int s = rw / 24;
    const ushort* row = qkv + ((size_t)(b*SEQ + s))*(2*DMODEL) + head*HD + li*4;
    ushort4 hv = *(const ushort4*)row;
    float h0 = bf2f(hv.x), h1 = bf2f(hv.y), h2 = bf2f(hv.z), h3 = bf2f(hv.w);
    float ss = (h0*h0 + h1*h1) + (h2*h2 + h3*h3);
    #pragma unroll
    for (int m=1; m<32; m<<=1) ss += __shfl_xor(ss, m);
    float rinv = rsqrtf(ss * (1.0f/128.0f) + 1e-6f);
    const float* wp = (head < NQH) ? qw : kw;
    float4 w4 = *(const float4*)(wp + li*4);
    float n0 = h0*rinv*w4.x, n1 = h1*rinv*w4.y, n2 = h2*rinv*w4.z, n3 = h3*rinv*w4.w;
    float p0 = __shfl_xor(n0, 16), p1 = __shfl_xor(n1, 16);
    float p2 = __shfl_xor(n2, 16), p3 = __shfl_xor(n3, 16);
    bool lo = (li < 16);
    float r0 = lo ? -p0 : p0, r1 = lo ? -p1 : p1;
    float r2 = lo ? -p2 : p2, r3 = lo ? -p3 : p3;
    float4 c4 = *(const float4*)(cosT + s*HD + li*4);
    float4 s4 = *(const float4*)(sinT + s*HD + li*4);
    float sc = (head < NQH) ? 0.12751656062f : 1.0f;  // 2^-3.5 * log2(e)
    uint2 o;
    o.x = cvtpk((n0*c4.x + r0*s4.x)*sc, (n1*c4.y + r1*s4.y)*sc);
    o.y = cvtpk((n2*c4.z + r2*s4.z)*sc, (n3*c4.w + r3*s4.w)*sc);
    if (head < NQH)
      *(uint2*)(Qo + ((size_t)((b*NQH + head)*SEQ) + s)*HD + li*4) = o;
    else
      *(uint2*)(Ko + ((size_t)((b*NKVH + (head-NQH))*SEQ) + s)*HD + li*4) = o;
  } else {
    __shared__ __align__(16) ushort t[64][136];
    int bid = blockIdx.x - 12288;
    int st = bid & 31, kh = (bid >> 5) & 7, b = bid >> 8;
    int s0 = st * 64;
    int tid = threadIdx.x;
    #pragma unroll
    for (int it=0; it<4; it++){
      int row = (tid >> 4) + it*16;
      int c = tid & 15;
      uint4 v = *(const uint4*)&qkv[((size_t)(b*SEQ + s0 + row))*(2*DMODEL) + (NQH+NKVH+kh)*HD + c*8];
      *(uint4*)&t[row][c*8] = v;
    }
    __syncthreads();
    #pragma unroll
    for (int it=0; it<4; it++){
      int g = it*256 + tid;
      int d = g >> 3, c = g & 7;
      ushort tmp[8] __attribute__((aligned(16)));
      #pragma unroll
      for (int j=0;j<8;j++) tmp[j] = t[c*8+j][d];
      *(uint4*)&vt[((size_t)((b*NKVH+kh)*HD + d))*SEQ + s0 + c*8] = *(uint4*)tmp;
    }
  }
}

// ---------------- causal flash attention, GQA, 32x32 MFMA (R10 chain-shortened) ----------------
__global__ __launch_bounds__(256, 2) void attn_fwd(const ushort* __restrict__ Q,
                                                   const ushort* __restrict__ Kb,
                                                   const ushort* __restrict__ Vt,
                                                   ushort* __restrict__ O){
  __shared__ __align__(16) ushort lK[2][64*128];
  __shared__ __align__(16) ushort lV[2][128*64];
  const int l = threadIdx.x & 63, w = threadIdx.x >> 6;
  const int wq = w >> 1, wkv = w & 1;
  const int hl = l >> 5, q32 = l & 31;
  const int lin = blockIdx.x;
  const int wg = (lin & 7) * 64 + (lin >> 3);   // bijective, nwg=512
  const int e = wg & 15, head = (wg >> 4) & 15, b = wg >> 8;
  const int kh = head >> 1;

  const ushort* kg = Kb + (size_t)((b*NKVH + kh)*SEQ) * HD;
  const ushort* vg = Vt + (size_t)((b*NKVH + kh)*HD) * SEQ;

  auto STAGE = [&](int t, int bi){
    const int kv0 = t*64;
    #pragma unroll
    for (int j=0;j<4;j++){
      int krow = kv0 + w*16 + j*4 + (l>>4);
      gload16(kg + (size_t)krow*HD + (((l&15) ^ (krow&15))<<3),
              &lK[bi][(w*16 + j*4)*128]);
      int vrow = w*32 + j*8 + (l>>3);
      gload16(vg + (size_t)vrow*SEQ + kv0 + (((l&7) ^ (l>>3))<<3),
              &lV[bi][(w*32 + j*8)*64]);
    }
  };

  auto run_tile = [&](int qt){
    const int qb = qt*64 + wq*32;
    const ushort* qp = Q + ((size_t)((b*NQH + head)*SEQ) + qb + q32) * HD + hl*8;
    bf16x8 qf[8];
    #pragma unroll
    for (int ks=0; ks<8; ks++) qf[ks] = *(const bf16x8*)(qp + ks*16);

    float mrun = -1e30f, lrun = 0.f;
    f32x16 acc[4];
    #pragma unroll
    for (int dt=0;dt<4;dt++)
      #pragma unroll
      for (int r=0;r<16;r++) acc[dt][r] = 0.f;

    STAGE(0, 0);

    for (int t=0; t<=qt; t++){
      const int bi = t & 1;
      if (t < qt){
        STAGE(t+1, bi^1);
        asm volatile("s_waitcnt vmcnt(8)" ::: "memory");
      } else {
        asm volatile("s_waitcnt vmcnt(0)" ::: "memory");
      }
      __builtin_amdgcn_s_barrier();

      const bool skip = (t==qt) && (wq==0) && (wkv==1);
      if (!skip){
        f32x16 sa, sb;
        #pragma unroll
        for (int r=0;r<16;r++){ sa[r] = 0.f; sb[r] = 0.f; }
        const int rowT = wkv*32 + q32;
        __builtin_amdgcn_s_setprio(1);
        #pragma unroll
        for (int ks=0; ks<4; ks++){
          int slot0 = (ks*2 + hl) ^ (rowT & 15);
          int slot1 = ((ks+4)*2 + hl) ^ (rowT & 15);
          bf16x8 kf0 = *(const bf16x8*)&lK[bi][rowT*128 + slot0*8];
          bf16x8 kf1 = *(const bf16x8*)&lK[bi][rowT*128 + slot1*8];
          sa = __builtin_amdgcn_mfma_f32_32x32x16_bf16(kf0, qf[ks],   sa, 0,0,0);
          sb = __builtin_amdgcn_mfma_f32_32x32x16_bf16(kf1, qf[ks+4], sb, 0,0,0);
        }
        __builtin_amdgcn_s_setprio(0);
        f32x16 s = sa + sb;
        if (t==qt && wq==wkv){
          const int qg = qb + q32;
          #pragma unroll
          for (int r=0;r<16;r++){
            int kvg = t*64 + wkv*32 + (r&3) + 8*(r>>2) + 4*hl;
            s[r] = (kvg > qg) ? -1e30f : s[r];
          }
        }
        float m0 = fmaxf(fmaxf(s[0],s[1]),s[2]);
        float m1 = fmaxf(fmaxf(s[3],s[4]),s[5]);
        float m2 = fmaxf(fmaxf(s[6],s[7]),s[8]);
        float m3 = fmaxf(fmaxf(s[9],s[10]),s[11]);
        float m4 = fmaxf(fmaxf(s[12],s[13]),s[14]);
        float tmax = fmaxf(fmaxf(fmaxf(m0,m1),fmaxf(m2,m3)),fmaxf(m4,s[15]));
        tmax = fmaxf(tmax, __shfl_xor(tmax, 32));
        if (!__all(tmax <= mrun + 8.f)){
          float mnew = fmaxf(mrun, tmax);
          float corr = __builtin_amdgcn_exp2f(mrun - mnew);
          mrun = mnew; lrun *= corr;
          #pragma unroll
          for (int r=0;r<16;r++){
            int qr = (r&3) + 8*(r>>2) + 4*hl;
            float cr = __shfl(corr, qr);
            acc[0][r]*=cr; acc[1][r]*=cr; acc[2][r]*=cr; acc[3][r]*=cr;
          }
        }
        #pragma unroll
        for (int r=0;r<16;r++) s[r] = __builtin_amdgcn_exp2f(s[r] - mrun);
        float r0s = (s[0]+s[1])+(s[2]+s[3]);
        float r1s = (s[4]+s[5])+(s[6]+s[7]);
        float r2s = (s[8]+s[9])+(s[10]+s[11]);
        float r3s = (s[12]+s[13])+(s[14]+s[15]);
        float rs = (r0s+r1s)+(r2s+r3s);
        rs += __shfl_xor(rs, 32);
        lrun += rs;
        union PWU { unsigned int u[4]; bf16x8 v; };
        PWU pw0, pw1;
        {
          unsigned int A = cvtpk(s[0], s[1]);
          unsigned int B = cvtpk(s[2], s[3]);
          unsigned int C = cvtpk(s[4], s[5]);
          unsigned int D = cvtpk(s[6], s[7]);
          auto sw0 = __builtin_amdgcn_permlane32_swap(A, C, false, false);
          auto sw1 = __builtin_amdgcn_permlane32_swap(B, D, false, false);
          pw0.u[0]=sw0[0]; pw0.u[1]=sw1[0]; pw0.u[2]=sw0[1]; pw0.u[3]=sw1[1];
        }
        {
          unsigned int A = cvtpk(s[8], s[9]);
          unsigned int B = cvtpk(s[10], s[11]);
          unsigned int C = cvtpk(s[12], s[13]);
          unsigned int D = cvtpk(s[14], s[15]);
          auto sw0 = __builtin_amdgcn_permlane32_swap(A, C, false, false);
          auto sw1 = __builtin_amdgcn_permlane32_swap(B, D, false, false);
          pw1.u[0]=sw0[0]; pw1.u[1]=sw1[0]; pw1.u[2]=sw0[1]; pw1.u[3]=sw1[1];
        }
        __builtin_amdgcn_s_setprio(1);
        #pragma unroll
        for (int dt=0; dt<4; dt++){
          int d = dt*32 + q32;
          int slot0 = (wkv*4 + 0 + hl) ^ (d & 7);
          bf16x8 vf0 = *(const bf16x8*)&lV[bi][d*64 + slot0*8];
          acc[dt] = __builtin_amdgcn_mfma_f32_32x32x16_bf16(pw0.v, vf0, acc[dt], 0,0,0);
        }
        #pragma unroll
        for (int dt=0; dt<4; dt++){
          int d = dt*32 + q32;
          int slot1 = (wkv*4 + 2 + hl) ^ (d & 7);
          bf16x8 vf1 = *(const bf16x8*)&lV[bi][d*64 + slot1*8];
          acc[dt] = __builtin_amdgcn_mfma_f32_32x32x16_bf16(pw1.v, vf1, acc[dt], 0,0,0);
        }
        __builtin_amdgcn_s_setprio(0);
      }
      asm volatile("s_waitcnt lgkmcnt(0)" ::: "memory");
      __builtin_amdgcn_s_barrier();
    }

    float* mergeO = (float*)(&lK[0][0]) + wq*4096;
    float* mergeML = (float*)(&lV[0][0]);
    if (wkv == 1){
      #pragma unroll
      for (int dt=0; dt<4; dt++)
        #pragma unroll
        for (int rg=0; rg<4; rg++){
          f32x4 o = { acc[dt][rg*4+0], acc[dt][rg*4+1], acc[dt][rg*4+2], acc[dt][rg*4+3] };
          *(f32x4*)&mergeO[(dt*4+rg)*256 + l*4] = o;
        }
      if (l < 32){
        mergeML[wq*64 + l] = mrun;
        mergeML[wq*64 + 32 + l] = lrun;
      }
    }
    __syncthreads();
    if (wkv == 0){
      float m1 = mergeML[wq*64 + q32];
      float l1 = mergeML[wq*64 + 32 + q32];
      float mf = fmaxf(mrun, m1);
      float c0 = __builtin_amdgcn_exp2f(mrun - mf);
      float c1 = __builtin_amdgcn_exp2f(m1 - mf);
      float lt = lrun*c0 + l1*c1;
      float linv = 1.0f / lt;
      float f0 = c0 * linv, f1 = c1 * linv;
      float g0a[16], g1a[16];
      #pragma unroll
      for (int r=0;r<16;r++){
        int qr = (r&3) + 8*(r>>2) + 4*hl;
        g0a[r] = __shfl(f0, qr);
        g1a[r] = __shfl(f1, qr);
      }
      #pragma unroll
      for (int dt=0; dt<4; dt++)
        #pragma unroll
        for (int rg=0; rg<4; rg++){
          f32x4 o1 = *(const f32x4*)&mergeO[(dt*4+rg)*256 + l*4];
          #pragma unroll
          for (int j=0;j<4;j++){
            int r = rg*4 + j;
            int qr = (r&3) + 8*(r>>2) + 4*hl;
            float val = acc[dt][r]*g0a[r] + o1[j]*g1a[r];
            int orow = qt*64 + wq*32 + qr;
            O[((size_t)(b*SEQ) + orow)*DMODEL + head*HD + dt*32 + q32] = f2bf(val);
          }
        }
    }
    __syncthreads();
  };

  run_tile(e);
  run_tile(31 - e);
}

extern "C" void kernel_launch(void* const* d_in, const int* in_sizes, int n_in,
                              void* d_out, int out_size, void* d_ws, size_t ws_size,
                              hipStream_t stream){
  const float* x    = (const float*)d_in[0];
  const float* pcos = (const float*)d_in[1];
  const float* psin = (const float*)d_in[2];
  const float* wqkv = (const float*)d_in[3];
  const float* wo   = (const float*)d_in[4];
  const float* qnw  = (const float*)d_in[5];
  const float* knw  = (const float*)d_in[6];
  char* ws = (char*)d_ws;

  ushort* xb    = (ushort*)(ws + 0);           // 16 MB
  ushort* wqkvb = (ushort*)(ws + 16777216);    // 16 MB
  ushort* wob   = (ushort*)(ws + 33554432);    // 8 MB
  ushort* qkv   = (ushort*)(ws + 41943040);    // 32 MB
  ushort* qbuf  = (ushort*)(ws + 75497472);    // 16 MB
  ushort* kbuf  = (ushort*)(ws + 92274688);    // 8 MB
  ushort* vtb   = (ushort*)(ws + 100663296);   // 8 MB
  ushort* aout  = (ushort*)(ws + 0);           // reuse xb region after QKV GEMM

  cvtbf3<<<10240, 256, 0, stream>>>(x, wqkv, wo, xb, wqkvb, wob);

  gemm256_bt<<<dim3(16,16), 512, 0, stream>>>(xb, wqkvb, qkv, 4096, 4096, 2048);

  nr_vt<<<12800, 256, 0, stream>>>(qkv, pcos, psin, qnw, knw, qbuf, kbuf, vtb);

  attn_fwd<<<dim3(512), 256, 0, stream>>>(qbuf, kbuf, vtb, aout);

  gemm_o<<<dim3(32,32), 256, 0, stream>>>(aout, wob, (float*)d_out, 4096, 2048, 2048);
}

// Round 19
// 192.821 us; speedup vs baseline: 1.0275x; 1.0275x over previous
//
#include <hip/hip_runtime.h>
#include <hip/hip_bf16.h>
#include <stdint.h>

#define HD 128
#define NQH 16
#define NKVH 8
#define SEQ 2048
#define DMODEL 2048
#define BATCH 2

typedef __attribute__((ext_vector_type(8))) short bf16x8;
typedef __attribute__((ext_vector_type(4))) float f32x4;
typedef __attribute__((ext_vector_type(16))) float f32x16;

__device__ __forceinline__ ushort f2bf(float f){
  union { float f; uint32_t u; } v; v.f = f;
  uint32_t u = v.u;
  return (ushort)((u + 0x7FFFu + ((u >> 16) & 1u)) >> 16);
}
__device__ __forceinline__ float bf2f(ushort h){
  union { uint32_t u; float f; } v; v.u = ((uint32_t)h) << 16; return v.f;
}
__device__ __forceinline__ void gload16(const void* g, void* l){
  __builtin_amdgcn_global_load_lds((const __attribute__((address_space(1))) void*)g,
                                   (__attribute__((address_space(3))) void*)l, 16, 0, 0);
}
__device__ __forceinline__ unsigned int cvtpk(float lo, float hi){
  unsigned int r;
  asm("v_cvt_pk_bf16_f32 %0, %1, %2" : "=v"(r) : "v"(lo), "v"(hi));
  return r;
}

// ---------------- fused fp32 -> bf16 convert (8 elems/thread, cvtpk) ----------------
__global__ void cvtbf3(const float* __restrict__ x, const float* __restrict__ wqkv,
                       const float* __restrict__ wo,
                       ushort* __restrict__ xb, ushort* __restrict__ wqkvb,
                       ushort* __restrict__ wob){
  int bid = blockIdx.x;
  const float* in; ushort* out; int i;
  if (bid < 4096)      { in = x;    out = xb;    i = bid*256 + threadIdx.x; }
  else if (bid < 8192) { in = wqkv; out = wqkvb; i = (bid-4096)*256 + threadIdx.x; }
  else                 { in = wo;   out = wob;   i = (bid-8192)*256 + threadIdx.x; }
  float4 a = ((const float4*)in)[i*2];
  float4 b = ((const float4*)in)[i*2+1];
  uint4 o;
  o.x = cvtpk(a.x, a.y);
  o.y = cvtpk(a.z, a.w);
  o.z = cvtpk(b.x, b.y);
  o.w = cvtpk(b.z, b.w);
  ((uint4*)out)[i] = o;
}

// ---------------- 128x128 bf16 GEMM (O-proj): C = A * B^T ----------------
template<int OUTF32>
__global__ __launch_bounds__(256) void gemm_bt(const ushort* __restrict__ A,
                                               const ushort* __restrict__ B,
                                               void* __restrict__ C,
                                               int M, int N, int K){
  __shared__ __align__(16) ushort lA[128*64];
  __shared__ __align__(16) ushort lB[128*64];
  const int tid = threadIdx.x;
  const int l = tid & 63, w = tid >> 6;
  const int nwg = gridDim.x * gridDim.y;
  const int lin = blockIdx.y * gridDim.x + blockIdx.x;
  const int wg = (lin & 7) * (nwg >> 3) + (lin >> 3);
  const int m0 = (wg / gridDim.x) * 128, n0 = (wg % gridDim.x) * 128;
  const int wr = (w >> 1) * 64, wc = (w & 1) * 64;
  f32x4 acc[4][4];
  #pragma unroll
  for (int m=0;m<4;m++)
    #pragma unroll
    for (int n=0;n<4;n++) acc[m][n] = f32x4{0.f,0.f,0.f,0.f};

  const int srow = l >> 3;
  const int scol = ((l & 7) ^ srow) << 3;
  const ushort* gA = A + (size_t)(m0 + w*32 + srow) * K + scol;
  const ushort* gB = B + (size_t)(n0 + w*32 + srow) * K + scol;
  ushort* lAw = &lA[(w*32) * 64];
  ushort* lBw = &lB[(w*32) * 64];

  for (int kt = 0; kt < K; kt += 64){
    __syncthreads();
    #pragma unroll
    for (int j=0;j<4;j++){
      gload16(gA + kt + (size_t)(j*8)*K, lAw + j*8*64);
      gload16(gB + kt + (size_t)(j*8)*K, lBw + j*8*64);
    }
    __syncthreads();
    #pragma unroll
    for (int kk=0; kk<2; kk++){
      bf16x8 af[4], bb[4];
      #pragma unroll
      for (int m=0;m<4;m++){
        int row = wr + m*16 + (l & 15);
        int slot = (kk*4 + (l >> 4)) ^ (row & 7);
        af[m] = *(const bf16x8*)&lA[row*64 + slot*8];
      }
      #pragma unroll
      for (int n=0;n<4;n++){
        int row = wc + n*16 + (l & 15);
        int slot = (kk*4 + (l >> 4)) ^ (row & 7);
        bb[n] = *(const bf16x8*)&lB[row*64 + slot*8];
      }
      #pragma unroll
      for (int m=0;m<4;m++)
        #pragma unroll
        for (int n=0;n<4;n++)
          acc[m][n] = __builtin_amdgcn_mfma_f32_16x16x32_bf16(af[m], bb[n], acc[m][n], 0,0,0);
    }
  }
  #pragma unroll
  for (int m=0;m<4;m++)
    #pragma unroll
    for (int n=0;n<4;n++)
      #pragma unroll
      for (int r=0;r<4;r++){
        size_t row = (size_t)(m0 + wr + m*16 + (l>>4)*4 + r);
        size_t col = (size_t)(n0 + wc + n*16 + (l & 15));
        float v = acc[m][n][r];
        if (OUTF32) ((float*)C)[row*N + col] = v;
        else        ((ushort*)C)[row*N + col] = f2bf(v);
      }
}

// ---------------- 256x256 8-phase bf16 GEMM (QKV): C = A * B^T, bf16 out ----------------
// 2-K-tile unrolled; XCD-aware block swizzle. Sync identical to R4. (R13 verified: 71.7us)
__global__ __launch_bounds__(512, 1) void gemm256_bt(const ushort* __restrict__ A,
                                                     const ushort* __restrict__ B,
                                                     ushort* __restrict__ C,
                                                     int M, int N, int K){
  __shared__ __align__(16) ushort lA[2][256*64];
  __shared__ __align__(16) ushort lB[2][256*64];
  const int tid = threadIdx.x;
  const int l = tid & 63, w = tid >> 6;
  const int wm = w >> 2, wn = w & 3;
  const int nwg = gridDim.x * gridDim.y;
  const int lin = blockIdx.y * gridDim.x + blockIdx.x;
  const int wg = (lin & 7) * (nwg >> 3) + (lin >> 3);
  const int m0 = (wg / gridDim.x) * 256, n0 = (wg % gridDim.x) * 256;
  const int NT = K >> 6;

  const int srow = w*8 + (l >> 3);
  const int scol = ((l & 7) ^ (l >> 3)) << 3;

  const int la15 = l & 15;
  const int sl0 = (((l >> 4)    ) ^ (l & 7)) * 8;
  const int sl1 = ((4 + (l >> 4)) ^ (l & 7)) * 8;

  f32x4 acc[8][4];
  #pragma unroll
  for (int m=0;m<8;m++)
    #pragma unroll
    for (int n=0;n<4;n++) acc[m][n] = f32x4{0.f,0.f,0.f,0.f};

  auto stgA = [&](int t, int h){
    const int bi = t & 1;
    #pragma unroll
    for (int j=0;j<2;j++)
      gload16(A + (size_t)(m0 + h*128 + j*64 + srow)*K + t*64 + scol,
              &lA[bi][(h*128 + j*64 + w*8)*64]);
  };
  auto stgB = [&](int t, int h){
    const int bi = t & 1;
    #pragma unroll
    for (int j=0;j<2;j++)
      gload16(B + (size_t)(n0 + h*128 + j*64 + srow)*K + t*64 + scol,
              &lB[bi][(h*128 + j*64 + w*8)*64]);
  };

  stgA(0,0); stgA(0,1); stgB(0,0); stgB(0,1);
  stgA(1,0); stgB(1,0); stgB(1,1);
  asm volatile("s_waitcnt vmcnt(6)" ::: "memory");
  __builtin_amdgcn_s_barrier();

  for (int t2=0; t2<NT; t2+=2){
    #pragma unroll
    for (int tt=0; tt<2; tt++){
      const int t = t2 + tt;                 // bi == tt (compile-time)
      const ushort* pA = &lA[tt][(wm*128 + la15)*64];
      const ushort* pB = &lB[tt][(wn*64  + la15)*64];
      bf16x8 bfr0[4], bfr1[4];
      #pragma unroll
      for (int q=0; q<4; q++){
        bf16x8 af0[2], af1[2];
        #pragma unroll
        for (int mi2=0; mi2<2; mi2++){
          af0[mi2] = *(const bf16x8*)(pA + (q*32 + mi2*16)*64 + sl0);
          af1[mi2] = *(const bf16x8*)(pA + (q*32 + mi2*16)*64 + sl1);
        }
        if (q == 0){
          #pragma unroll
          for (int ni=0; ni<4; ni++){
            bfr0[ni] = *(const bf16x8*)(pB + ni*16*64 + sl0);
            bfr1[ni] = *(const bf16x8*)(pB + ni*16*64 + sl1);
          }
        }
        if (q == 0 && t+1 < NT) stgA(t+1, 1);
        if (q == 1 && t+2 < NT) stgB(t+2, 0);
        if (q == 2 && t+2 < NT) stgB(t+2, 1);
        __builtin_amdgcn_s_barrier();
        asm volatile("s_waitcnt lgkmcnt(0)" ::: "memory");
        if (q == 3 && t+2 < NT) stgA(t+2, 0);
        __builtin_amdgcn_s_setprio(1);
        #pragma unroll
        for (int mi2=0; mi2<2; mi2++)
          #pragma unroll
          for (int ni=0; ni<4; ni++)
            acc[q*2+mi2][ni] = __builtin_amdgcn_mfma_f32_16x16x32_bf16(
                af0[mi2], bfr0[ni], acc[q*2+mi2][ni], 0,0,0);
        #pragma unroll
        for (int mi2=0; mi2<2; mi2++)
          #pragma unroll
          for (int ni=0; ni<4; ni++)
            acc[q*2+mi2][ni] = __builtin_amdgcn_mfma_f32_16x16x32_bf16(
                af1[mi2], bfr1[ni], acc[q*2+mi2][ni], 0,0,0);
        __builtin_amdgcn_s_setprio(0);
        if (q == 3){
          if (t < NT-2) { asm volatile("s_waitcnt vmcnt(6)" ::: "memory"); }
          else          { asm volatile("s_waitcnt vmcnt(0)" ::: "memory"); }
        }
        __builtin_amdgcn_s_barrier();
      }
    }
  }

  #pragma unroll
  for (int mi=0; mi<8; mi++)
    #pragma unroll
    for (int ni=0; ni<4; ni++)
      #pragma unroll
      for (int r=0; r<4; r++){
        size_t row = (size_t)(m0 + wm*128 + mi*16 + (l>>4)*4 + r);
        size_t col = (size_t)(n0 + wn*64 + ni*16 + (l & 15));
        C[row*N + col] = f2bf(acc[mi][ni][r]);
      }
}

// ---------------- fused RMSNorm+RoPE (blocks 0..12287) + V-transpose (12288..12799) ----------------
__global__ __launch_bounds__(256) void nr_vt(const ushort* __restrict__ qkv,
                                             const float* __restrict__ cosT,
                                             const float* __restrict__ sinT,
                                             const float* __restrict__ qw,
                                             const float* __restrict__ kw,
                                             ushort* __restrict__ Qo,
                                             ushort* __restrict__ Ko,
                                             ushort* __restrict__ vt){
  if (blockIdx.x < 12288){
    int rw = (blockIdx.x * 256 + threadIdx.x) >> 6;
    int l = threadIdx.x & 63;
    int b = l >> 5;
    int li = l & 31;
    int head = rw % 24;
    int s = rw / 24;
    const ushort* row = qkv + ((size_t)(b*SEQ + s))*(2*DMODEL) + head*HD + li*4;
    ushort4 hv = *(const ushort4*)row;
    float h0 = bf2f(hv.x), h1 = bf2f(hv.y), h2 = bf2f(hv.z), h3 = bf2f(hv.w);
    float ss = (h0*h0 + h1*h1) + (h2*h2 + h3*h3);
    #pragma unroll
    for (int m=1; m<32; m<<=1) ss += __shfl_xor(ss, m);
    float rinv = rsqrtf(ss * (1.0f/128.0f) + 1e-6f);
    const float* wp = (head < NQH) ? qw : kw;
    float4 w4 = *(const float4*)(wp + li*4);
    float n0 = h0*rinv*w4.x, n1 = h1*rinv*w4.y, n2 = h2*rinv*w4.z, n3 = h3*rinv*w4.w;
    float p0 = __shfl_xor(n0, 16), p1 = __shfl_xor(n1, 16);
    float p2 = __shfl_xor(n2, 16), p3 = __shfl_xor(n3, 16);
    bool lo = (li < 16);
    float r0 = lo ? -p0 : p0, r1 = lo ? -p1 : p1;
    float r2 = lo ? -p2 : p2, r3 = lo ? -p3 : p3;
    float4 c4 = *(const float4*)(cosT + s*HD + li*4);
    float4 s4 = *(const float4*)(sinT + s*HD + li*4);
    float sc = (head < NQH) ? 0.12751656062f : 1.0f;  // 2^-3.5 * log2(e)
    uint2 o;
    o.x = cvtpk((n0*c4.x + r0*s4.x)*sc, (n1*c4.y + r1*s4.y)*sc);
    o.y = cvtpk((n2*c4.z + r2*s4.z)*sc, (n3*c4.w + r3*s4.w)*sc);
    if (head < NQH)
      *(uint2*)(Qo + ((size_t)((b*NQH + head)*SEQ) + s)*HD + li*4) = o;
    else
      *(uint2*)(Ko + ((size_t)((b*NKVH + (head-NQH))*SEQ) + s)*HD + li*4) = o;
  } else {
    __shared__ __align__(16) ushort t[64][136];
    int bid = blockIdx.x - 12288;
    int st = bid & 31, kh = (bid >> 5) & 7, b = bid >> 8;
    int s0 = st * 64;
    int tid = threadIdx.x;
    #pragma unroll
    for (int it=0; it<4; it++){
      int row = (tid >> 4) + it*16;
      int c = tid & 15;
      uint4 v = *(const uint4*)&qkv[((size_t)(b*SEQ + s0 + row))*(2*DMODEL) + (NQH+NKVH+kh)*HD + c*8];
      *(uint4*)&t[row][c*8] = v;
    }
    __syncthreads();
    #pragma unroll
    for (int it=0; it<4; it++){
      int g = it*256 + tid;
      int d = g >> 3, c = g & 7;
      ushort tmp[8] __attribute__((aligned(16)));
      #pragma unroll
      for (int j=0;j<8;j++) tmp[j] = t[c*8+j][d];
      *(uint4*)&vt[((size_t)((b*NKVH+kh)*HD + d))*SEQ + s0 + c*8] = *(uint4*)tmp;
    }
  }
}

// ---------------- causal flash attention, GQA, 32x32 MFMA (R10 chain-shortened) ----------------
__global__ __launch_bounds__(256, 2) void attn_fwd(const ushort* __restrict__ Q,
                                                   const ushort* __restrict__ Kb,
                                                   const ushort* __restrict__ Vt,
                                                   ushort* __restrict__ O){
  __shared__ __align__(16) ushort lK[2][64*128];
  __shared__ __align__(16) ushort lV[2][128*64];
  const int l = threadIdx.x & 63, w = threadIdx.x >> 6;
  const int wq = w >> 1, wkv = w & 1;
  const int hl = l >> 5, q32 = l & 31;
  const int lin = blockIdx.x;
  const int wg = (lin & 7) * 64 + (lin >> 3);   // bijective, nwg=512
  const int e = wg & 15, head = (wg >> 4) & 15, b = wg >> 8;
  const int kh = head >> 1;

  const ushort* kg = Kb + (size_t)((b*NKVH + kh)*SEQ) * HD;
  const ushort* vg = Vt + (size_t)((b*NKVH + kh)*HD) * SEQ;

  auto STAGE = [&](int t, int bi){
    const int kv0 = t*64;
    #pragma unroll
    for (int j=0;j<4;j++){
      int krow = kv0 + w*16 + j*4 + (l>>4);
      gload16(kg + (size_t)krow*HD + (((l&15) ^ (krow&15))<<3),
              &lK[bi][(w*16 + j*4)*128]);
      int vrow = w*32 + j*8 + (l>>3);
      gload16(vg + (size_t)vrow*SEQ + kv0 + (((l&7) ^ (l>>3))<<3),
              &lV[bi][(w*32 + j*8)*64]);
    }
  };

  auto run_tile = [&](int qt){
    const int qb = qt*64 + wq*32;
    const ushort* qp = Q + ((size_t)((b*NQH + head)*SEQ) + qb + q32) * HD + hl*8;
    bf16x8 qf[8];
    #pragma unroll
    for (int ks=0; ks<8; ks++) qf[ks] = *(const bf16x8*)(qp + ks*16);

    float mrun = -1e30f, lrun = 0.f;
    f32x16 acc[4];
    #pragma unroll
    for (int dt=0;dt<4;dt++)
      #pragma unroll
      for (int r=0;r<16;r++) acc[dt][r] = 0.f;

    STAGE(0, 0);

    for (int t=0; t<=qt; t++){
      const int bi = t & 1;
      if (t < qt){
        STAGE(t+1, bi^1);
        asm volatile("s_waitcnt vmcnt(8)" ::: "memory");
      } else {
        asm volatile("s_waitcnt vmcnt(0)" ::: "memory");
      }
      __builtin_amdgcn_s_barrier();

      const bool skip = (t==qt) && (wq==0) && (wkv==1);
      if (!skip){
        f32x16 sa, sb;
        #pragma unroll
        for (int r=0;r<16;r++){ sa[r] = 0.f; sb[r] = 0.f; }
        const int rowT = wkv*32 + q32;
        __builtin_amdgcn_s_setprio(1);
        #pragma unroll
        for (int ks=0; ks<4; ks++){
          int slot0 = (ks*2 + hl) ^ (rowT & 15);
          int slot1 = ((ks+4)*2 + hl) ^ (rowT & 15);
          bf16x8 kf0 = *(const bf16x8*)&lK[bi][rowT*128 + slot0*8];
          bf16x8 kf1 = *(const bf16x8*)&lK[bi][rowT*128 + slot1*8];
          sa = __builtin_amdgcn_mfma_f32_32x32x16_bf16(kf0, qf[ks],   sa, 0,0,0);
          sb = __builtin_amdgcn_mfma_f32_32x32x16_bf16(kf1, qf[ks+4], sb, 0,0,0);
        }
        __builtin_amdgcn_s_setprio(0);
        f32x16 s = sa + sb;
        if (t==qt && wq==wkv){
          const int qg = qb + q32;
          #pragma unroll
          for (int r=0;r<16;r++){
            int kvg = t*64 + wkv*32 + (r&3) + 8*(r>>2) + 4*hl;
            s[r] = (kvg > qg) ? -1e30f : s[r];
          }
        }
        float m0 = fmaxf(fmaxf(s[0],s[1]),s[2]);
        float m1 = fmaxf(fmaxf(s[3],s[4]),s[5]);
        float m2 = fmaxf(fmaxf(s[6],s[7]),s[8]);
        float m3 = fmaxf(fmaxf(s[9],s[10]),s[11]);
        float m4 = fmaxf(fmaxf(s[12],s[13]),s[14]);
        float tmax = fmaxf(fmaxf(fmaxf(m0,m1),fmaxf(m2,m3)),fmaxf(m4,s[15]));
        tmax = fmaxf(tmax, __shfl_xor(tmax, 32));
        if (!__all(tmax <= mrun + 8.f)){
          float mnew = fmaxf(mrun, tmax);
          float corr = __builtin_amdgcn_exp2f(mrun - mnew);
          mrun = mnew; lrun *= corr;
          #pragma unroll
          for (int r=0;r<16;r++){
            int qr = (r&3) + 8*(r>>2) + 4*hl;
            float cr = __shfl(corr, qr);
            acc[0][r]*=cr; acc[1][r]*=cr; acc[2][r]*=cr; acc[3][r]*=cr;
          }
        }
        #pragma unroll
        for (int r=0;r<16;r++) s[r] = __builtin_amdgcn_exp2f(s[r] - mrun);
        float r0s = (s[0]+s[1])+(s[2]+s[3]);
        float r1s = (s[4]+s[5])+(s[6]+s[7]);
        float r2s = (s[8]+s[9])+(s[10]+s[11]);
        float r3s = (s[12]+s[13])+(s[14]+s[15]);
        float rs = (r0s+r1s)+(r2s+r3s);
        rs += __shfl_xor(rs, 32);
        lrun += rs;
        union PWU { unsigned int u[4]; bf16x8 v; };
        PWU pw0, pw1;
        {
          unsigned int A = cvtpk(s[0], s[1]);
          unsigned int B = cvtpk(s[2], s[3]);
          unsigned int C = cvtpk(s[4], s[5]);
          unsigned int D = cvtpk(s[6], s[7]);
          auto sw0 = __builtin_amdgcn_permlane32_swap(A, C, false, false);
          auto sw1 = __builtin_amdgcn_permlane32_swap(B, D, false, false);
          pw0.u[0]=sw0[0]; pw0.u[1]=sw1[0]; pw0.u[2]=sw0[1]; pw0.u[3]=sw1[1];
        }
        {
          unsigned int A = cvtpk(s[8], s[9]);
          unsigned int B = cvtpk(s[10], s[11]);
          unsigned int C = cvtpk(s[12], s[13]);
          unsigned int D = cvtpk(s[14], s[15]);
          auto sw0 = __builtin_amdgcn_permlane32_swap(A, C, false, false);
          auto sw1 = __builtin_amdgcn_permlane32_swap(B, D, false, false);
          pw1.u[0]=sw0[0]; pw1.u[1]=sw1[0]; pw1.u[2]=sw0[1]; pw1.u[3]=sw1[1];
        }
        __builtin_amdgcn_s_setprio(1);
        #pragma unroll
        for (int dt=0; dt<4; dt++){
          int d = dt*32 + q32;
          int slot0 = (wkv*4 + 0 + hl) ^ (d & 7);
          bf16x8 vf0 = *(const bf16x8*)&lV[bi][d*64 + slot0*8];
          acc[dt] = __builtin_amdgcn_mfma_f32_32x32x16_bf16(pw0.v, vf0, acc[dt], 0,0,0);
        }
        #pragma unroll
        for (int dt=0; dt<4; dt++){
          int d = dt*32 + q32;
          int slot1 = (wkv*4 + 2 + hl) ^ (d & 7);
          bf16x8 vf1 = *(const bf16x8*)&lV[bi][d*64 + slot1*8];
          acc[dt] = __builtin_amdgcn_mfma_f32_32x32x16_bf16(pw1.v, vf1, acc[dt], 0,0,0);
        }
        __builtin_amdgcn_s_setprio(0);
      }
      asm volatile("s_waitcnt lgkmcnt(0)" ::: "memory");
      __builtin_amdgcn_s_barrier();
    }

    float* mergeO = (float*)(&lK[0][0]) + wq*4096;
    float* mergeML = (float*)(&lV[0][0]);
    if (wkv == 1){
      #pragma unroll
      for (int dt=0; dt<4; dt++)
        #pragma unroll
        for (int rg=0; rg<4; rg++){
          f32x4 o = { acc[dt][rg*4+0], acc[dt][rg*4+1], acc[dt][rg*4+2], acc[dt][rg*4+3] };
          *(f32x4*)&mergeO[(dt*4+rg)*256 + l*4] = o;
        }
      if (l < 32){
        mergeML[wq*64 + l] = mrun;
        mergeML[wq*64 + 32 + l] = lrun;
      }
    }
    __syncthreads();
    if (wkv == 0){
      float m1 = mergeML[wq*64 + q32];
      float l1 = mergeML[wq*64 + 32 + q32];
      float mf = fmaxf(mrun, m1);
      float c0 = __builtin_amdgcn_exp2f(mrun - mf);
      float c1 = __builtin_amdgcn_exp2f(m1 - mf);
      float lt = lrun*c0 + l1*c1;
      float linv = 1.0f / lt;
      float f0 = c0 * linv, f1 = c1 * linv;
      float g0a[16], g1a[16];
      #pragma unroll
      for (int r=0;r<16;r++){
        int qr = (r&3) + 8*(r>>2) + 4*hl;
        g0a[r] = __shfl(f0, qr);
        g1a[r] = __shfl(f1, qr);
      }
      #pragma unroll
      for (int dt=0; dt<4; dt++)
        #pragma unroll
        for (int rg=0; rg<4; rg++){
          f32x4 o1 = *(const f32x4*)&mergeO[(dt*4+rg)*256 + l*4];
          #pragma unroll
          for (int j=0;j<4;j++){
            int r = rg*4 + j;
            int qr = (r&3) + 8*(r>>2) + 4*hl;
            float val = acc[dt][r]*g0a[r] + o1[j]*g1a[r];
            int orow = qt*64 + wq*32 + qr;
            O[((size_t)(b*SEQ) + orow)*DMODEL + head*HD + dt*32 + q32] = f2bf(val);
          }
        }
    }
    __syncthreads();
  };

  run_tile(e);
  run_tile(31 - e);
}

extern "C" void kernel_launch(void* const* d_in, const int* in_sizes, int n_in,
                              void* d_out, int out_size, void* d_ws, size_t ws_size,
                              hipStream_t stream){
  const float* x    = (const float*)d_in[0];
  const float* pcos = (const float*)d_in[1];
  const float* psin = (const float*)d_in[2];
  const float* wqkv = (const float*)d_in[3];
  const float* wo   = (const float*)d_in[4];
  const float* qnw  = (const float*)d_in[5];
  const float* knw  = (const float*)d_in[6];
  char* ws = (char*)d_ws;

  ushort* xb    = (ushort*)(ws + 0);           // 16 MB
  ushort* wqkvb = (ushort*)(ws + 16777216);    // 16 MB
  ushort* wob   = (ushort*)(ws + 33554432);    // 8 MB
  ushort* qkv   = (ushort*)(ws + 41943040);    // 32 MB
  ushort* qbuf  = (ushort*)(ws + 75497472);    // 16 MB
  ushort* kbuf  = (ushort*)(ws + 92274688);    // 8 MB
  ushort* vtb   = (ushort*)(ws + 100663296);   // 8 MB
  ushort* aout  = (ushort*)(ws + 0);           // reuse xb region after QKV GEMM

  cvtbf3<<<10240, 256, 0, stream>>>(x, wqkv, wo, xb, wqkvb, wob);

  gemm256_bt<<<dim3(16,16), 512, 0, stream>>>(xb, wqkvb, qkv, 4096, 4096, 2048);

  nr_vt<<<12800, 256, 0, stream>>>(qkv, pcos, psin, qnw, knw, qbuf, kbuf, vtb);

  attn_fwd<<<dim3(512), 256, 0, stream>>>(qbuf, kbuf, vtb, aout);

  gemm_bt<1><<<dim3(16,32), 256, 0, stream>>>(aout, wob, d_out, 4096, 2048, 2048);
}